// Round 1
// baseline (671.444 us; speedup 1.0000x reference)
//
#include <hip/hip_runtime.h>
#include <math.h>

// IPA: B=1, N=768, H=12, C=16, PQ=4, PV=8, C_S=384, C_Z=128
// ws layout (floats):
//   raw  [768][1152]  q|k|v|qp|kp|vp concatenated (matches GEMM col order)
//   qpts [768][144], kpts [768][144], vpts [768][288] (global-frame points)
//   qn/kn [768][12], cat [768][2016], partial [4][768][384]
#define RAW_OFF   0u
#define QPTS_OFF  884736u
#define KPTS_OFF  995328u
#define VPTS_OFF  1105920u
#define QN_OFF    1327104u
#define KN_OFF    1336320u
#define CAT_OFF   1345536u
#define PART_OFF  2893824u
// total ws need: 4,073,472 floats = 16.3 MB

#define WL 0.5773502691896258f    // sqrt(1/3)
#define WC 0.23570226039551587f   // sqrt(2/(9*4))

// ---------------- kernel 1: s @ [Wq|Wk|Wv|Wqp|Wkp|Wvp] -> raw ----------------
__global__ __launch_bounds__(256) void prep_gemm(
    const float* __restrict__ s, const float* __restrict__ Wq, const float* __restrict__ Wk,
    const float* __restrict__ Wv, const float* __restrict__ Wqp, const float* __restrict__ Wkp,
    const float* __restrict__ Wvp, float* __restrict__ raw)
{
  int t = threadIdx.x;
  int bc = blockIdx.x % 24;       // col tile (48 cols) -- 48 divides every matrix boundary
  int br = blockIdx.x / 24;       // row tile (32 rows)
  int row0 = br * 32;
  int cb = bc * 48;
  const float* W; int outdim, c0;
  if (cb < 192)      { W = Wq;  outdim = 192; c0 = cb; }
  else if (cb < 384) { W = Wk;  outdim = 192; c0 = cb - 192; }
  else if (cb < 576) { W = Wv;  outdim = 192; c0 = cb - 384; }
  else if (cb < 720) { W = Wqp; outdim = 144; c0 = cb - 576; }
  else if (cb < 864) { W = Wkp; outdim = 144; c0 = cb - 720; }
  else               { W = Wvp; outdim = 288; c0 = cb - 864; }

  __shared__ float s_l[32*33];
  __shared__ float w_l[32*49];
  float acc[2][3] = {};
  int tr = t >> 4, tc = t & 15;

  for (int k0 = 0; k0 < 384; k0 += 32) {
    #pragma unroll
    for (int i = 0; i < 4; ++i) {                 // stage s 32x32
      int idx = i*256 + t;
      int r = idx >> 5, kk = idx & 31;
      s_l[r*33 + kk] = s[(row0 + r)*384 + k0 + kk];
    }
    #pragma unroll
    for (int i = 0; i < 6; ++i) {                 // stage W 32x48
      int idx = i*256 + t;
      int kk = idx / 48, c = idx % 48;
      w_l[kk*49 + c] = W[(k0 + kk)*outdim + c0 + c];
    }
    __syncthreads();
    #pragma unroll
    for (int kk = 0; kk < 32; ++kk) {
      float a0 = s_l[(tr*2+0)*33 + kk];
      float a1 = s_l[(tr*2+1)*33 + kk];
      float b0 = w_l[kk*49 + tc*3 + 0];
      float b1 = w_l[kk*49 + tc*3 + 1];
      float b2 = w_l[kk*49 + tc*3 + 2];
      acc[0][0] += a0*b0; acc[0][1] += a0*b1; acc[0][2] += a0*b2;
      acc[1][0] += a1*b0; acc[1][1] += a1*b1; acc[1][2] += a1*b2;
    }
    __syncthreads();
  }
  #pragma unroll
  for (int i = 0; i < 2; ++i)
    #pragma unroll
    for (int j = 0; j < 3; ++j)
      raw[(row0 + tr*2 + i)*1152 + cb + tc*3 + j] = acc[i][j];
}

// ---------------- kernel 2: frame transform + point norms ----------------
__global__ __launch_bounds__(256) void transform_pts(
    const float* __restrict__ raw, const float* __restrict__ R, const float* __restrict__ tg,
    float* __restrict__ qpts, float* __restrict__ kpts, float* __restrict__ vpts,
    float* __restrict__ qn, float* __restrict__ kn)
{
  int n = blockIdx.x, t = threadIdx.x;
  __shared__ float tl[576];
  const float* R9 = R + n*9;
  const float* tv = tg + n*3;
  for (int i = 0; i < 3; ++i) {
    int j = i*256 + t;
    if (j >= 576) break;
    int jj, basecol; float* dst; int dstoff;
    if (j < 144)      { jj = j;      basecol = 576; dst = qpts; dstoff = n*144 + jj; }
    else if (j < 288) { jj = j-144;  basecol = 720; dst = kpts; dstoff = n*144 + jj; }
    else              { jj = j-288;  basecol = 864; dst = vpts; dstoff = n*288 + jj; }
    int x = jj % 3;
    const float* p = raw + n*1152 + basecol + (jj - x);
    float val = R9[x*3+0]*p[0] + R9[x*3+1]*p[1] + R9[x*3+2]*p[2] + tv[x];
    dst[dstoff] = val;
    tl[j] = val;
  }
  __syncthreads();
  if (t < 24) {
    int side = t / 12, h = t % 12;
    const float* q = tl + side*144 + h*12;
    float sm = 0.f;
    #pragma unroll
    for (int r = 0; r < 12; ++r) sm += q[r]*q[r];
    (side == 0 ? qn : kn)[n*12 + h] = sm;
  }
}

// ---------------- kernel 3: fused attention, one block per query row ----------------
__global__ __launch_bounds__(256) void ipa_main(
    const float* __restrict__ z, const float* __restrict__ raw,
    const float* __restrict__ qpts, const float* __restrict__ kpts,
    const float* __restrict__ vpts, const float* __restrict__ kn,
    const float* __restrict__ Wb, const float* __restrict__ Rg,
    const float* __restrict__ tg, float* __restrict__ cat)
{
  int n = blockIdx.x, t = threadIdx.x;
  __shared__ __align__(16) float z_l[64*129];   // pad 129: odd stride -> conflict-free scalar access
  __shared__ __align__(16) float wb_l[128*12];
  __shared__ float part[4*12*66];               // bias partials; reused for o_pair partials at end
  __shared__ __align__(16) float w_l2[64*12];   // probs p[m][h]
  __shared__ float q_l[12*17];
  __shared__ float qp_l[12*13];
  __shared__ float S_l[12];
  __shared__ float ogl[288];

  // init
  if (t < 192) q_l[(t>>4)*17 + (t&15)] = raw[n*1152 + t];
  if (t < 144) qp_l[(t/12)*13 + (t%12)] = qpts[n*144 + t];
  if (t < 12) S_l[t] = 0.f;
  #pragma unroll
  for (int i = 0; i < 6; ++i) wb_l[i*256 + t] = Wb[i*256 + t];

  // D-phase entry decode: entry e1 = t (o for t<192 else og), e2 = t+256 (og)
  int h1, h2 = 0; const float* p1; const float* p2 = nullptr; int st1;
  if (t < 192) { h1 = t >> 4; p1 = raw + 384 + t; st1 = 1152; }
  else         { h1 = (t - 192) / 24; p1 = vpts + (t - 192); st1 = 288; }
  bool has2 = (t < 224);
  if (has2) { h2 = (t + 64) / 24; p2 = vpts + (t + 64); }
  float acc1 = 0.f, acc2 = 0.f;
  float op[12];
  #pragma unroll
  for (int h = 0; h < 12; ++h) op[h] = 0.f;
  int zi = t & 127, ms = t >> 7;

  const float* zrow = z + ((size_t)n*768)*128;

  for (int m0 = 0; m0 < 768; m0 += 64) {
    // ---- stage z tile 64x128 ----
    #pragma unroll
    for (int i = 0; i < 8; ++i) {
      int f4 = i*256 + t;
      int m = f4 >> 5, c4 = f4 & 31;
      float4 v = *(const float4*)(zrow + (m0 + m)*128 + c4*4);
      float* d = z_l + m*129 + c4*4;
      d[0] = v.x; d[1] = v.y; d[2] = v.z; d[3] = v.w;
    }
    __syncthreads();

    // ---- B1: bias partials (each z element read once; Wb wave-uniform bcast) ----
    {
      int zq = t >> 6, m = t & 63;
      float bias[12];
      #pragma unroll
      for (int h = 0; h < 12; ++h) bias[h] = 0.f;
      const float* zr = z_l + m*129 + zq*32;
      const float4* wb4 = (const float4*)(wb_l + zq*384);
      #pragma unroll 4
      for (int zz = 0; zz < 32; ++zz) {
        float zv = zr[zz];
        float4 w0 = wb4[zz*3+0], w1 = wb4[zz*3+1], w2 = wb4[zz*3+2];
        bias[0] += zv*w0.x; bias[1] += zv*w0.y; bias[2] += zv*w0.z; bias[3] += zv*w0.w;
        bias[4] += zv*w1.x; bias[5] += zv*w1.y; bias[6] += zv*w1.z; bias[7] += zv*w1.w;
        bias[8] += zv*w2.x; bias[9] += zv*w2.y; bias[10]+= zv*w2.z; bias[11]+= zv*w2.w;
      }
      #pragma unroll
      for (int h = 0; h < 12; ++h) part[zq*792 + h*66 + m] = bias[h];
    }
    __syncthreads();

    // ---- B2: logits -> p = exp(logit) (qn term dropped: softmax shift-invariant) ----
    #pragma unroll
    for (int i = 0; i < 3; ++i) {
      int idx = i*256 + t;
      int m = idx / 12, h = idx % 12;
      int kr = m0 + m;
      const float4* kv = (const float4*)(raw + kr*1152 + 192 + h*16);
      float4 k0 = kv[0], k1 = kv[1], k2 = kv[2], k3 = kv[3];
      const float* qh = q_l + h*17;
      float qk = k0.x*qh[0] + k0.y*qh[1] + k0.z*qh[2] + k0.w*qh[3]
               + k1.x*qh[4] + k1.y*qh[5] + k1.z*qh[6] + k1.w*qh[7]
               + k2.x*qh[8] + k2.y*qh[9] + k2.z*qh[10]+ k2.w*qh[11]
               + k3.x*qh[12]+ k3.y*qh[13]+ k3.z*qh[14]+ k3.w*qh[15];
      const float4* kp = (const float4*)(kpts + kr*144 + h*12);
      float4 kp0 = kp[0], kp1 = kp[1], kp2 = kp[2];
      const float* qp = qp_l + h*13;
      float cross = kp0.x*qp[0] + kp0.y*qp[1] + kp0.z*qp[2] + kp0.w*qp[3]
                  + kp1.x*qp[4] + kp1.y*qp[5] + kp1.z*qp[6] + kp1.w*qp[7]
                  + kp2.x*qp[8] + kp2.y*qp[9] + kp2.z*qp[10]+ kp2.w*qp[11];
      float knv = kn[kr*12 + h];
      float bias = part[h*66 + m] + part[792 + h*66 + m]
                 + part[1584 + h*66 + m] + part[2376 + h*66 + m];
      float logit = WL*(qk*0.25f + bias - 0.5f*WC*(knv - 2.f*cross));
      w_l2[m*12 + h] = __expf(logit);
    }
    __syncthreads();

    // ---- SM-lite: accumulate softmax denominator (wave 0 only; C/D don't read S_l) ----
    if (t < 48) {
      int h = t >> 2, seg = t & 3;
      float ps = 0.f;
      #pragma unroll
      for (int i = 0; i < 16; ++i) ps += w_l2[(seg*16 + i)*12 + h];
      ps += __shfl_xor(ps, 1);
      ps += __shfl_xor(ps, 2);
      if (seg == 0) S_l[h] += ps;
    }

    // ---- C: o_pair accumulate (z element read once; p as bcast float4) ----
    #pragma unroll 4
    for (int m = ms; m < 64; m += 2) {
      const float4* wp = (const float4*)(w_l2 + m*12);
      float4 wa = wp[0], wbv = wp[1], wcv = wp[2];
      float zv = z_l[m*129 + zi];
      op[0] += wa.x*zv;  op[1] += wa.y*zv;  op[2]  += wa.z*zv;  op[3]  += wa.w*zv;
      op[4] += wbv.x*zv; op[5] += wbv.y*zv; op[6]  += wbv.z*zv; op[7]  += wbv.w*zv;
      op[8] += wcv.x*zv; op[9] += wcv.y*zv; op[10] += wcv.z*zv; op[11] += wcv.w*zv;
    }

    // ---- D: o / o_pts accumulate (v, vpts L2-resident) ----
    #pragma unroll 4
    for (int m = 0; m < 64; ++m) {
      float w1 = w_l2[m*12 + h1];
      acc1 += w1 * p1[(size_t)(m0 + m)*st1];
      if (has2) {
        float w2 = w_l2[m*12 + h2];
        acc2 += w2 * p2[(size_t)(m0 + m)*288];
      }
    }
    __syncthreads();
  }

  // ---- finalize ----
  float* catn = cat + (size_t)n*2016;
  if (t < 192) catn[t] = acc1 / S_l[h1];
  else         ogl[t - 192] = acc1 / S_l[h1];
  if (has2)    ogl[t + 64]  = acc2 / S_l[h2];
  #pragma unroll
  for (int h = 0; h < 12; ++h) part[ms*1536 + h*128 + zi] = op[h];
  __syncthreads();

  const float* R9 = Rg + n*9;
  const float* tv = tg + n*3;
  for (int j = t; j < 288; j += 256) {
    int x = (j % 24) % 3;
    int base = j - x;
    float g0 = ogl[base+0] - tv[0];
    float g1 = ogl[base+1] - tv[1];
    float g2 = ogl[base+2] - tv[2];
    catn[192 + j] = R9[x]*g0 + R9[3+x]*g1 + R9[6+x]*g2;   // R^T (g - t)
  }
  #pragma unroll
  for (int i = 0; i < 6; ++i) {
    int e = i*256 + t;
    int h = e >> 7;
    catn[480 + e] = (part[e] + part[1536 + e]) / S_l[h];
  }
}

// ---------------- kernel 4: cat @ W_out (split-K x4) ----------------
__global__ __launch_bounds__(256) void final_gemm(
    const float* __restrict__ cat, const float* __restrict__ Wout, float* __restrict__ partial)
{
  int t = threadIdx.x;
  int b = blockIdx.x;
  int ct = b % 6, rt = (b / 6) % 12, ks = b / 72;
  int r0 = rt*64, c0 = ct*64, kbase = ks*504;
  __shared__ float a_l[64*25];
  __shared__ float b_l[24*65];
  float acc[4][4] = {};
  int tr = t >> 4, tc = t & 15;
  for (int kt = 0; kt < 504; kt += 24) {
    int k0 = kbase + kt;
    #pragma unroll
    for (int i = 0; i < 6; ++i) {
      int idx = i*256 + t;
      int r = idx / 24, kk = idx % 24;
      a_l[r*25 + kk] = cat[(size_t)(r0 + r)*2016 + k0 + kk];
      int kk2 = idx >> 6, c = idx & 63;
      b_l[kk2*65 + c] = Wout[(size_t)(k0 + kk2)*384 + c0 + c];
    }
    __syncthreads();
    #pragma unroll
    for (int kk = 0; kk < 24; ++kk) {
      float a[4], bb[4];
      #pragma unroll
      for (int i = 0; i < 4; ++i) a[i] = a_l[(tr*4+i)*25 + kk];
      #pragma unroll
      for (int j = 0; j < 4; ++j) bb[j] = b_l[kk*65 + tc*4 + j];
      #pragma unroll
      for (int i = 0; i < 4; ++i)
        #pragma unroll
        for (int j = 0; j < 4; ++j) acc[i][j] += a[i]*bb[j];
    }
    __syncthreads();
  }
  float* po = partial + (size_t)ks*294912;
  #pragma unroll
  for (int i = 0; i < 4; ++i)
    #pragma unroll
    for (int j = 0; j < 4; ++j)
      po[(r0 + tr*4 + i)*384 + c0 + tc*4 + j] = acc[i][j];
}

// ---------------- kernel 5: reduce partials + bias ----------------
__global__ __launch_bounds__(256) void reduce_out(
    const float* __restrict__ partial, const float* __restrict__ b_out, float* __restrict__ out)
{
  int i = blockIdx.x*256 + threadIdx.x;   // 294912 total
  out[i] = b_out[i % 384] + partial[i] + partial[294912 + i]
         + partial[2*294912 + i] + partial[3*294912 + i];
}

extern "C" void kernel_launch(void* const* d_in, const int* in_sizes, int n_in,
                              void* d_out, int out_size, void* d_ws, size_t ws_size,
                              hipStream_t stream) {
  const float* s    = (const float*)d_in[0];
  const float* z    = (const float*)d_in[1];
  const float* R    = (const float*)d_in[2];
  const float* tv   = (const float*)d_in[3];
  const float* Wq   = (const float*)d_in[4];
  const float* Wk   = (const float*)d_in[5];
  const float* Wv   = (const float*)d_in[6];
  const float* Wqp  = (const float*)d_in[7];
  const float* Wkp  = (const float*)d_in[8];
  const float* Wvp  = (const float*)d_in[9];
  const float* Wb   = (const float*)d_in[10];
  const float* Wout = (const float*)d_in[11];
  const float* bout = (const float*)d_in[12];
  float* out = (float*)d_out;
  float* ws  = (float*)d_ws;

  float* raw  = ws + RAW_OFF;
  float* qpts = ws + QPTS_OFF;
  float* kpts = ws + KPTS_OFF;
  float* vpts = ws + VPTS_OFF;
  float* qn   = ws + QN_OFF;
  float* kn   = ws + KN_OFF;
  float* cat  = ws + CAT_OFF;
  float* partial = ws + PART_OFF;

  prep_gemm<<<576, 256, 0, stream>>>(s, Wq, Wk, Wv, Wqp, Wkp, Wvp, raw);
  transform_pts<<<768, 256, 0, stream>>>(raw, R, tv, qpts, kpts, vpts, qn, kn);
  ipa_main<<<768, 256, 0, stream>>>(z, raw, qpts, kpts, vpts, kn, Wb, R, tv, cat);
  final_gemm<<<288, 256, 0, stream>>>(cat, Wout, partial);
  reduce_out<<<1152, 256, 0, stream>>>(partial, bout, out);
}

// Round 2
// 514.956 us; speedup vs baseline: 1.3039x; 1.3039x over previous
//
#include <hip/hip_runtime.h>
#include <math.h>

// IPA: B=1, N=768, H=12, C=16, PQ=4, PV=8, C_S=384, C_Z=128
// ws layout (floats):
//   raw  [768][1152]  q|k|v|qp|kp|vp concatenated (matches GEMM col order)
//   qpts [768][144], kpts [768][144], vpts [768][288] (global-frame points)
//   qn/kn [768][12], cat [768][2016], partial [4][768][384]
#define RAW_OFF   0u
#define QPTS_OFF  884736u
#define KPTS_OFF  995328u
#define VPTS_OFF  1105920u
#define QN_OFF    1327104u
#define KN_OFF    1336320u
#define CAT_OFF   1345536u
#define PART_OFF  2893824u

#define WL 0.5773502691896258f    // sqrt(1/3)
#define WC 0.23570226039551587f   // sqrt(2/(9*4))

// ---------------- kernel 1: s @ [Wq|Wk|Wv|Wqp|Wkp|Wvp] -> raw ----------------
__global__ __launch_bounds__(256) void prep_gemm(
    const float* __restrict__ s, const float* __restrict__ Wq, const float* __restrict__ Wk,
    const float* __restrict__ Wv, const float* __restrict__ Wqp, const float* __restrict__ Wkp,
    const float* __restrict__ Wvp, float* __restrict__ raw)
{
  int t = threadIdx.x;
  int bc = blockIdx.x % 24;       // col tile (48 cols)
  int br = blockIdx.x / 24;       // row tile (32 rows)
  int row0 = br * 32;
  int cb = bc * 48;
  const float* W; int outdim, c0;
  if (cb < 192)      { W = Wq;  outdim = 192; c0 = cb; }
  else if (cb < 384) { W = Wk;  outdim = 192; c0 = cb - 192; }
  else if (cb < 576) { W = Wv;  outdim = 192; c0 = cb - 384; }
  else if (cb < 720) { W = Wqp; outdim = 144; c0 = cb - 576; }
  else if (cb < 864) { W = Wkp; outdim = 144; c0 = cb - 720; }
  else               { W = Wvp; outdim = 288; c0 = cb - 864; }

  __shared__ float s_l[32*33];
  __shared__ float w_l[32*49];
  float acc[2][3] = {};
  int tr = t >> 4, tc = t & 15;

  for (int k0 = 0; k0 < 384; k0 += 32) {
    #pragma unroll
    for (int i = 0; i < 4; ++i) {
      int idx = i*256 + t;
      int r = idx >> 5, kk = idx & 31;
      s_l[r*33 + kk] = s[(row0 + r)*384 + k0 + kk];
    }
    #pragma unroll
    for (int i = 0; i < 6; ++i) {
      int idx = i*256 + t;
      int kk = idx / 48, c = idx % 48;
      w_l[kk*49 + c] = W[(k0 + kk)*outdim + c0 + c];
    }
    __syncthreads();
    #pragma unroll
    for (int kk = 0; kk < 32; ++kk) {
      float a0 = s_l[(tr*2+0)*33 + kk];
      float a1 = s_l[(tr*2+1)*33 + kk];
      float b0 = w_l[kk*49 + tc*3 + 0];
      float b1 = w_l[kk*49 + tc*3 + 1];
      float b2 = w_l[kk*49 + tc*3 + 2];
      acc[0][0] += a0*b0; acc[0][1] += a0*b1; acc[0][2] += a0*b2;
      acc[1][0] += a1*b0; acc[1][1] += a1*b1; acc[1][2] += a1*b2;
    }
    __syncthreads();
  }
  #pragma unroll
  for (int i = 0; i < 2; ++i)
    #pragma unroll
    for (int j = 0; j < 3; ++j)
      raw[(row0 + tr*2 + i)*1152 + cb + tc*3 + j] = acc[i][j];
}

// ---------------- kernel 2: frame transform + point norms ----------------
__global__ __launch_bounds__(256) void transform_pts(
    const float* __restrict__ raw, const float* __restrict__ R, const float* __restrict__ tg,
    float* __restrict__ qpts, float* __restrict__ kpts, float* __restrict__ vpts,
    float* __restrict__ qn, float* __restrict__ kn)
{
  int n = blockIdx.x, t = threadIdx.x;
  __shared__ float tl[576];
  const float* R9 = R + n*9;
  const float* tv = tg + n*3;
  for (int i = 0; i < 3; ++i) {
    int j = i*256 + t;
    if (j >= 576) break;
    int jj, basecol; float* dst; int dstoff;
    if (j < 144)      { jj = j;      basecol = 576; dst = qpts; dstoff = n*144 + jj; }
    else if (j < 288) { jj = j-144;  basecol = 720; dst = kpts; dstoff = n*144 + jj; }
    else              { jj = j-288;  basecol = 864; dst = vpts; dstoff = n*288 + jj; }
    int x = jj % 3;
    const float* p = raw + n*1152 + basecol + (jj - x);
    float val = R9[x*3+0]*p[0] + R9[x*3+1]*p[1] + R9[x*3+2]*p[2] + tv[x];
    dst[dstoff] = val;
    tl[j] = val;
  }
  __syncthreads();
  if (t < 24) {
    int side = t / 12, h = t % 12;
    const float* q = tl + side*144 + h*12;
    float sm = 0.f;
    #pragma unroll
    for (int r = 0; r < 12; ++r) sm += q[r]*q[r];
    (side == 0 ? qn : kn)[n*12 + h] = sm;
  }
}

// ---------------- kernel 3: fused attention, one block per query row ----------------
// T14 reg-staged double buffering: issue next z-tile global loads into VGPRs
// before compute phases; write regs->LDS (padded-129 layout) after last barrier.
// wb_l dropped from LDS (wave-uniform L1-resident global reads) => 51.4 KB LDS
// => 3 blocks/CU (launch_bounds(256,3), VGPR cap 170).
__global__ __launch_bounds__(256, 3) void ipa_main(
    const float* __restrict__ z, const float* __restrict__ raw,
    const float* __restrict__ qpts, const float* __restrict__ kpts,
    const float* __restrict__ vpts, const float* __restrict__ kn,
    const float* __restrict__ Wb, const float* __restrict__ Rg,
    const float* __restrict__ tg, float* __restrict__ cat)
{
  int n = blockIdx.x, t = threadIdx.x;
  __shared__ __align__(16) float z_l[64*129];   // pad 129: conflict-free scalar access
  __shared__ float part[4*12*66];               // bias partials; reused for o_pair at end
  __shared__ __align__(16) float w_l2[64*12];   // probs p[m][h]
  __shared__ float q_l[12*17];
  __shared__ float qp_l[12*13];
  __shared__ float S_l[12];
  __shared__ float ogl[288];

  // init
  if (t < 192) q_l[(t>>4)*17 + (t&15)] = raw[n*1152 + t];
  if (t < 144) qp_l[(t/12)*13 + (t%12)] = qpts[n*144 + t];
  if (t < 12) S_l[t] = 0.f;

  // D-phase entry decode
  int h1, h2 = 0; const float* p1; const float* p2 = nullptr; int st1;
  if (t < 192) { h1 = t >> 4; p1 = raw + 384 + t; st1 = 1152; }
  else         { h1 = (t - 192) / 24; p1 = vpts + (t - 192); st1 = 288; }
  bool has2 = (t < 224);
  if (has2) { h2 = (t + 64) / 24; p2 = vpts + (t + 64); }
  float acc1 = 0.f, acc2 = 0.f;
  float op[12];
  #pragma unroll
  for (int h = 0; h < 12; ++h) op[h] = 0.f;
  int zi = t & 127, ms = t >> 7;

  const float* zrow = z + ((size_t)n*768)*128;
  int sm_ = (t>>5), sc4 = t & 31;               // staging decode: m = i*8 + sm_, col4 = sc4

  float4 zst[8];
  #define STAGE_LOAD(M0)                                            \
    _Pragma("unroll")                                               \
    for (int i = 0; i < 8; ++i)                                     \
      zst[i] = *(const float4*)(zrow + ((M0) + i*8 + sm_)*128 + sc4*4);
  #define STAGE_WRITE()                                             \
    _Pragma("unroll")                                               \
    for (int i = 0; i < 8; ++i) {                                   \
      float* d = z_l + (i*8 + sm_)*129 + sc4*4;                     \
      d[0]=zst[i].x; d[1]=zst[i].y; d[2]=zst[i].z; d[3]=zst[i].w;   \
    }

  // prologue: tile 0
  STAGE_LOAD(0);
  STAGE_WRITE();
  __syncthreads();

  for (int it = 0; it < 12; ++it) {
    int m0 = it*64;
    if (it + 1 < 12) { STAGE_LOAD(m0 + 64); }   // issue early; hides under B1..D

    // ---- B1: bias partials (each z element read once; Wb L1-broadcast) ----
    {
      int zq = t >> 6, m = t & 63;
      float bias[12];
      #pragma unroll
      for (int h = 0; h < 12; ++h) bias[h] = 0.f;
      const float* zr = z_l + m*129 + zq*32;
      const float4* wb4 = (const float4*)(Wb + zq*384);   // wave-uniform
      #pragma unroll 4
      for (int zz = 0; zz < 32; ++zz) {
        float zv = zr[zz];
        float4 w0 = wb4[zz*3+0], w1 = wb4[zz*3+1], w2 = wb4[zz*3+2];
        bias[0] += zv*w0.x; bias[1] += zv*w0.y; bias[2] += zv*w0.z; bias[3] += zv*w0.w;
        bias[4] += zv*w1.x; bias[5] += zv*w1.y; bias[6] += zv*w1.z; bias[7] += zv*w1.w;
        bias[8] += zv*w2.x; bias[9] += zv*w2.y; bias[10]+= zv*w2.z; bias[11]+= zv*w2.w;
      }
      #pragma unroll
      for (int h = 0; h < 12; ++h) part[zq*792 + h*66 + m] = bias[h];
    }
    __syncthreads();

    // ---- B2: logits -> p = exp(logit) (qn dropped: softmax shift-invariant) ----
    #pragma unroll
    for (int i = 0; i < 3; ++i) {
      int idx = i*256 + t;
      int m = idx / 12, h = idx % 12;
      int kr = m0 + m;
      const float4* kv = (const float4*)(raw + kr*1152 + 192 + h*16);
      float4 k0 = kv[0], k1 = kv[1], k2 = kv[2], k3 = kv[3];
      const float* qh = q_l + h*17;
      float qk = k0.x*qh[0] + k0.y*qh[1] + k0.z*qh[2] + k0.w*qh[3]
               + k1.x*qh[4] + k1.y*qh[5] + k1.z*qh[6] + k1.w*qh[7]
               + k2.x*qh[8] + k2.y*qh[9] + k2.z*qh[10]+ k2.w*qh[11]
               + k3.x*qh[12]+ k3.y*qh[13]+ k3.z*qh[14]+ k3.w*qh[15];
      const float4* kp = (const float4*)(kpts + kr*144 + h*12);
      float4 kp0 = kp[0], kp1 = kp[1], kp2 = kp[2];
      const float* qp = qp_l + h*13;
      float cross = kp0.x*qp[0] + kp0.y*qp[1] + kp0.z*qp[2] + kp0.w*qp[3]
                  + kp1.x*qp[4] + kp1.y*qp[5] + kp1.z*qp[6] + kp1.w*qp[7]
                  + kp2.x*qp[8] + kp2.y*qp[9] + kp2.z*qp[10]+ kp2.w*qp[11];
      float knv = kn[kr*12 + h];
      float bias = part[h*66 + m] + part[792 + h*66 + m]
                 + part[1584 + h*66 + m] + part[2376 + h*66 + m];
      float logit = WL*(qk*0.25f + bias - 0.5f*WC*(knv - 2.f*cross));
      w_l2[m*12 + h] = __expf(logit);
    }
    __syncthreads();

    // ---- SM-lite: softmax denominator (wave 0; C/D don't read S_l) ----
    if (t < 48) {
      int h = t >> 2, seg = t & 3;
      float ps = 0.f;
      #pragma unroll
      for (int i = 0; i < 16; ++i) ps += w_l2[(seg*16 + i)*12 + h];
      ps += __shfl_xor(ps, 1);
      ps += __shfl_xor(ps, 2);
      if (seg == 0) S_l[h] += ps;
    }

    // ---- C: o_pair accumulate ----
    #pragma unroll 4
    for (int m = ms; m < 64; m += 2) {
      const float4* wp = (const float4*)(w_l2 + m*12);
      float4 wa = wp[0], wbv = wp[1], wcv = wp[2];
      float zv = z_l[m*129 + zi];
      op[0] += wa.x*zv;  op[1] += wa.y*zv;  op[2]  += wa.z*zv;  op[3]  += wa.w*zv;
      op[4] += wbv.x*zv; op[5] += wbv.y*zv; op[6]  += wbv.z*zv; op[7]  += wbv.w*zv;
      op[8] += wcv.x*zv; op[9] += wcv.y*zv; op[10] += wcv.z*zv; op[11] += wcv.w*zv;
    }

    // ---- D: o / o_pts accumulate (v, vpts L2-resident) ----
    #pragma unroll 4
    for (int m = 0; m < 64; ++m) {
      float w1 = w_l2[m*12 + h1];
      acc1 += w1 * p1[(size_t)(m0 + m)*st1];
      if (has2) {
        float w2 = w_l2[m*12 + h2];
        acc2 += w2 * p2[(size_t)(m0 + m)*288];
      }
    }
    __syncthreads();

    if (it + 1 < 12) {   // write prefetched tile (compiler inserts vmcnt wait)
      STAGE_WRITE();
      __syncthreads();
    }
  }

  // ---- finalize ----
  float* catn = cat + (size_t)n*2016;
  if (t < 192) catn[t] = acc1 / S_l[h1];
  else         ogl[t - 192] = acc1 / S_l[h1];
  if (has2)    ogl[t + 64]  = acc2 / S_l[h2];
  #pragma unroll
  for (int h = 0; h < 12; ++h) part[ms*1536 + h*128 + zi] = op[h];
  __syncthreads();

  const float* R9 = Rg + n*9;
  const float* tv = tg + n*3;
  for (int j = t; j < 288; j += 256) {
    int x = (j % 24) % 3;
    int base = j - x;
    float g0 = ogl[base+0] - tv[0];
    float g1 = ogl[base+1] - tv[1];
    float g2 = ogl[base+2] - tv[2];
    catn[192 + j] = R9[x]*g0 + R9[3+x]*g1 + R9[6+x]*g2;   // R^T (g - t)
  }
  #pragma unroll
  for (int i = 0; i < 6; ++i) {
    int e = i*256 + t;
    int h = e >> 7;
    catn[480 + e] = (part[e] + part[1536 + e]) / S_l[h];
  }
}

// ---------------- kernel 4: cat @ W_out (split-K x4) ----------------
__global__ __launch_bounds__(256) void final_gemm(
    const float* __restrict__ cat, const float* __restrict__ Wout, float* __restrict__ partial)
{
  int t = threadIdx.x;
  int b = blockIdx.x;
  int ct = b % 6, rt = (b / 6) % 12, ks = b / 72;
  int r0 = rt*64, c0 = ct*64, kbase = ks*504;
  __shared__ float a_l[64*25];
  __shared__ float b_l[24*65];
  float acc[4][4] = {};
  int tr = t >> 4, tc = t & 15;
  for (int kt = 0; kt < 504; kt += 24) {
    int k0 = kbase + kt;
    #pragma unroll
    for (int i = 0; i < 6; ++i) {
      int idx = i*256 + t;
      int r = idx / 24, kk = idx % 24;
      a_l[r*25 + kk] = cat[(size_t)(r0 + r)*2016 + k0 + kk];
      int kk2 = idx >> 6, c = idx & 63;
      b_l[kk2*65 + c] = Wout[(size_t)(k0 + kk2)*384 + c0 + c];
    }
    __syncthreads();
    #pragma unroll
    for (int kk = 0; kk < 24; ++kk) {
      float a[4], bb[4];
      #pragma unroll
      for (int i = 0; i < 4; ++i) a[i] = a_l[(tr*4+i)*25 + kk];
      #pragma unroll
      for (int j = 0; j < 4; ++j) bb[j] = b_l[kk*65 + tc*4 + j];
      #pragma unroll
      for (int i = 0; i < 4; ++i)
        #pragma unroll
        for (int j = 0; j < 4; ++j) acc[i][j] += a[i]*bb[j];
    }
    __syncthreads();
  }
  float* po = partial + (size_t)ks*294912;
  #pragma unroll
  for (int i = 0; i < 4; ++i)
    #pragma unroll
    for (int j = 0; j < 4; ++j)
      po[(r0 + tr*4 + i)*384 + c0 + tc*4 + j] = acc[i][j];
}

// ---------------- kernel 5: reduce partials + bias ----------------
__global__ __launch_bounds__(256) void reduce_out(
    const float* __restrict__ partial, const float* __restrict__ b_out, float* __restrict__ out)
{
  int i = blockIdx.x*256 + threadIdx.x;   // 294912 total
  out[i] = b_out[i % 384] + partial[i] + partial[294912 + i]
         + partial[2*294912 + i] + partial[3*294912 + i];
}

extern "C" void kernel_launch(void* const* d_in, const int* in_sizes, int n_in,
                              void* d_out, int out_size, void* d_ws, size_t ws_size,
                              hipStream_t stream) {
  const float* s    = (const float*)d_in[0];
  const float* z    = (const float*)d_in[1];
  const float* R    = (const float*)d_in[2];
  const float* tv   = (const float*)d_in[3];
  const float* Wq   = (const float*)d_in[4];
  const float* Wk   = (const float*)d_in[5];
  const float* Wv   = (const float*)d_in[6];
  const float* Wqp  = (const float*)d_in[7];
  const float* Wkp  = (const float*)d_in[8];
  const float* Wvp  = (const float*)d_in[9];
  const float* Wb   = (const float*)d_in[10];
  const float* Wout = (const float*)d_in[11];
  const float* bout = (const float*)d_in[12];
  float* out = (float*)d_out;
  float* ws  = (float*)d_ws;

  float* raw  = ws + RAW_OFF;
  float* qpts = ws + QPTS_OFF;
  float* kpts = ws + KPTS_OFF;
  float* vpts = ws + VPTS_OFF;
  float* qn   = ws + QN_OFF;
  float* kn   = ws + KN_OFF;
  float* cat  = ws + CAT_OFF;
  float* partial = ws + PART_OFF;

  prep_gemm<<<576, 256, 0, stream>>>(s, Wq, Wk, Wv, Wqp, Wkp, Wvp, raw);
  transform_pts<<<768, 256, 0, stream>>>(raw, R, tv, qpts, kpts, vpts, qn, kn);
  ipa_main<<<768, 256, 0, stream>>>(z, raw, qpts, kpts, vpts, kn, Wb, R, tv, cat);
  final_gemm<<<288, 256, 0, stream>>>(cat, Wout, partial);
  reduce_out<<<1152, 256, 0, stream>>>(partial, bout, out);
}

// Round 5
// 422.952 us; speedup vs baseline: 1.5875x; 1.2175x over previous
//
#include <hip/hip_runtime.h>
#include <math.h>

// IPA: B=1, N=768, H=12, C=16, PQ=4, PV=8, C_S=384, C_Z=128
// ws layout (floats):
#define RAW_OFF   0u          // [768][1152] q|k|v|qp|kp|vp
#define QPTS_OFF  884736u     // [768][144]
#define KPTS_OFF  995328u     // [768][144]
#define VPTS_OFF  1105920u    // [768][288]
#define QN_OFF    1327104u    // [768][12] (unused downstream, kept)
#define KN_OFF    1336320u    // [768][12]
#define CAT_OFF   1345536u    // [768][2016]
#define QP_OFF    2893824u    // bf16 [768][12][32] (147456 float slots)
#define KP_OFF    3041280u    // bf16 [768][12][32]
#define SLOG_OFF  3188736u    // f32 [768][768][12] = 7077888 floats
#define PART_OFF  3188736u    // alias slog (dead by final_gemm)
// total ws: 10,266,624 floats = 41.1 MB

#define WL 0.5773502691896258f    // sqrt(1/3)
#define WC 0.23570226039551587f   // sqrt(2/(9*4))
#define CKN (-0.5f*WL*WC)

typedef __attribute__((ext_vector_type(8))) short short8;
typedef __attribute__((ext_vector_type(4))) float f32x4;

__device__ __forceinline__ unsigned short f2bf1(float a) {
  unsigned u = __builtin_bit_cast(unsigned, a);
  return (unsigned short)((u + 0x7fff + ((u >> 16) & 1)) >> 16);
}
__device__ __forceinline__ unsigned f2bf2(float a, float b) {
  unsigned ua = __builtin_bit_cast(unsigned, a), ub = __builtin_bit_cast(unsigned, b);
  return (unsigned)((ua + 0x7fff + ((ua >> 16) & 1)) >> 16)
       | ((ub + 0x7fff + ((ub >> 16) & 1)) & 0xffff0000u);
}
__device__ __forceinline__ float bflo(unsigned u) { return __builtin_bit_cast(float, u << 16); }
__device__ __forceinline__ float bfhi(unsigned u) { return __builtin_bit_cast(float, u & 0xffff0000u); }

// LDS-only barrier: waitcnt+barrier in ONE asm so nothing schedules between
// them and no memory op crosses either side. Leaves global loads in flight.
#define BAR_LDS() asm volatile("s_waitcnt lgkmcnt(0)\n\ts_barrier" ::: "memory")

// ---------------- kernel 1: s @ [Wq|Wk|Wv|Wqp|Wkp|Wvp] -> raw ----------------
__global__ __launch_bounds__(256) void prep_gemm(
    const float* __restrict__ s, const float* __restrict__ Wq, const float* __restrict__ Wk,
    const float* __restrict__ Wv, const float* __restrict__ Wqp, const float* __restrict__ Wkp,
    const float* __restrict__ Wvp, float* __restrict__ raw)
{
  int t = threadIdx.x;
  int bc = blockIdx.x % 24, br = blockIdx.x / 24;
  int row0 = br * 32, cb = bc * 48;
  const float* W; int outdim, c0;
  if (cb < 192)      { W = Wq;  outdim = 192; c0 = cb; }
  else if (cb < 384) { W = Wk;  outdim = 192; c0 = cb - 192; }
  else if (cb < 576) { W = Wv;  outdim = 192; c0 = cb - 384; }
  else if (cb < 720) { W = Wqp; outdim = 144; c0 = cb - 576; }
  else if (cb < 864) { W = Wkp; outdim = 144; c0 = cb - 720; }
  else               { W = Wvp; outdim = 288; c0 = cb - 864; }

  __shared__ float s_l[32*33];
  __shared__ float w_l[32*49];
  float acc[2][3] = {};
  int tr = t >> 4, tc = t & 15;

  for (int k0 = 0; k0 < 384; k0 += 32) {
    #pragma unroll
    for (int i = 0; i < 4; ++i) {
      int idx = i*256 + t, r = idx >> 5, kk = idx & 31;
      s_l[r*33 + kk] = s[(row0 + r)*384 + k0 + kk];
    }
    #pragma unroll
    for (int i = 0; i < 6; ++i) {
      int idx = i*256 + t, kk = idx / 48, c = idx % 48;
      w_l[kk*49 + c] = W[(k0 + kk)*outdim + c0 + c];
    }
    __syncthreads();
    #pragma unroll
    for (int kk = 0; kk < 32; ++kk) {
      float a0 = s_l[(tr*2+0)*33 + kk], a1 = s_l[(tr*2+1)*33 + kk];
      float b0 = w_l[kk*49 + tc*3 + 0], b1 = w_l[kk*49 + tc*3 + 1], b2 = w_l[kk*49 + tc*3 + 2];
      acc[0][0] += a0*b0; acc[0][1] += a0*b1; acc[0][2] += a0*b2;
      acc[1][0] += a1*b0; acc[1][1] += a1*b1; acc[1][2] += a1*b2;
    }
    __syncthreads();
  }
  #pragma unroll
  for (int i = 0; i < 2; ++i)
    #pragma unroll
    for (int j = 0; j < 3; ++j)
      raw[(row0 + tr*2 + i)*1152 + cb + tc*3 + j] = acc[i][j];
}

// ---------------- kernel 2: frame transform + point norms ----------------
__global__ __launch_bounds__(256) void transform_pts(
    const float* __restrict__ raw, const float* __restrict__ R, const float* __restrict__ tg,
    float* __restrict__ qpts, float* __restrict__ kpts, float* __restrict__ vpts,
    float* __restrict__ qn, float* __restrict__ kn)
{
  int n = blockIdx.x, t = threadIdx.x;
  __shared__ float tl[576];
  const float* R9 = R + n*9;
  const float* tv = tg + n*3;
  for (int i = 0; i < 3; ++i) {
    int j = i*256 + t;
    if (j >= 576) break;
    int jj, basecol; float* dst; int dstoff;
    if (j < 144)      { jj = j;      basecol = 576; dst = qpts; dstoff = n*144 + jj; }
    else if (j < 288) { jj = j-144;  basecol = 720; dst = kpts; dstoff = n*144 + jj; }
    else              { jj = j-288;  basecol = 864; dst = vpts; dstoff = n*288 + jj; }
    int x = jj % 3;
    const float* p = raw + n*1152 + basecol + (jj - x);
    float val = R9[x*3+0]*p[0] + R9[x*3+1]*p[1] + R9[x*3+2]*p[2] + tv[x];
    dst[dstoff] = val;
    tl[j] = val;
  }
  __syncthreads();
  if (t < 24) {
    int side = t / 12, h = t % 12;
    const float* q = tl + side*144 + h*12;
    float sm = 0.f;
    #pragma unroll
    for (int r = 0; r < 12; ++r) sm += q[r]*q[r];
    (side == 0 ? qn : kn)[n*12 + h] = sm;
  }
}

// ---------------- kernel 3: build Qp/Kp bf16 [n][h][32] ----------------
// Qp = [WL*0.25*q(16) | WL*WC*qpts(12) | 0,0,0,0], Kp = [k | kpts | 0...]
__global__ __launch_bounds__(384) void qkprep(
    const float* __restrict__ raw, const float* __restrict__ qpts,
    const float* __restrict__ kpts, short* __restrict__ Qp, short* __restrict__ Kp)
{
  int n = blockIdx.x, t = threadIdx.x;
  int h = t >> 5, k = t & 31;
  float qv, kv;
  // raw cols: q 0..191, k 192..383, v 384..575  (ROUND-4 FIX: k at +192, not +384)
  if (k < 16)      { qv = (WL*0.25f) * raw[n*1152 + h*16 + k];       kv = raw[n*1152 + 192 + h*16 + k]; }
  else if (k < 28) { qv = (WL*WC) * qpts[n*144 + h*12 + (k-16)];     kv = kpts[n*144 + h*12 + (k-16)]; }
  else             { qv = 0.f; kv = 0.f; }
  Qp[n*384 + t] = (short)f2bf1(qv);
  Kp[n*384 + t] = (short)f2bf1(kv);
}

// ---------------- kernel 4: slog[n][m][12] = WL*(qk/4 + WC*cross) + CKN*kn ----------------
// per-h bf16 MFMA GEMM 768x768x32; block = 64x64 tile, 8 waves (4 nsub x 2 msub)
__global__ __launch_bounds__(512) void logits_gemm(
    const short* __restrict__ Qp, const short* __restrict__ Kp,
    const float* __restrict__ kn, float* __restrict__ slog)
{
  int t = threadIdx.x, b = blockIdx.x;
  int bn = b / 12, bm = b % 12;
  int lane = t & 63, wid = t >> 6;
  int nsub = wid & 3, msub = wid >> 2;
  int l15 = lane & 15, kg = lane >> 4;
  int nrow = bn*64 + nsub*16 + l15;
  int mbase = bm*64 + msub*32;

  f32x4 acc[2][12];
  #pragma unroll
  for (int mt = 0; mt < 2; ++mt)
    #pragma unroll
    for (int h = 0; h < 12; ++h) acc[mt][h] = (f32x4){0.f,0.f,0.f,0.f};

  #pragma unroll
  for (int h = 0; h < 12; ++h) {
    short8 af = *(const short8*)(Qp + (size_t)(nrow*12 + h)*32 + kg*8);
    #pragma unroll
    for (int mt = 0; mt < 2; ++mt) {
      int m = mbase + mt*16 + l15;
      short8 bf = *(const short8*)(Kp + (size_t)(m*12 + h)*32 + kg*8);
      acc[mt][h] = __builtin_amdgcn_mfma_f32_16x16x32_bf16(af, bf, acc[mt][h], 0, 0, 0);
    }
  }
  #pragma unroll
  for (int mt = 0; mt < 2; ++mt) {
    int m = mbase + mt*16 + l15;
    float knadj[12];
    #pragma unroll
    for (int h = 0; h < 12; ++h) knadj[h] = CKN * kn[m*12 + h];
    #pragma unroll
    for (int r = 0; r < 4; ++r) {
      int nr = bn*64 + nsub*16 + kg*4 + r;
      size_t base = ((size_t)nr*768 + m)*12;
      #pragma unroll
      for (int hq = 0; hq < 3; ++hq) {
        float4 v;
        v.x = acc[mt][hq*4+0][r] + knadj[hq*4+0];
        v.y = acc[mt][hq*4+1][r] + knadj[hq*4+1];
        v.z = acc[mt][hq*4+2][r] + knadj[hq*4+2];
        v.w = acc[mt][hq*4+3][r] + knadj[hq*4+3];
        *(float4*)(slog + base + hq*4) = v;
      }
    }
  }
}

// ---------------- kernel 5: fused attention core ----------------
// LDS (u32 words): z_l bf16 [64][pitch68w], bias[64][17], w_l2[64][16],
//                  w_mt[16][68], S[12], ogl[288], dred[480]
#define Z_L   0
#define BIASL 4352
#define W_L2  5440
#define W_MT  6464
#define S_L   7552
#define OGL   7564
#define DRED  7852
#define SMEMW 8332

__global__ __launch_bounds__(256, 4) void ipa_main(
    const float* __restrict__ z, const float* __restrict__ raw,
    const float* __restrict__ slog, const float* __restrict__ vpts,
    const float* __restrict__ Wb, const float* __restrict__ Rg,
    const float* __restrict__ tg, float* __restrict__ cat)
{
  __shared__ __align__(16) unsigned smem[SMEMW];
  float* smf = (float*)smem;
  int n = blockIdx.x, t = threadIdx.x;
  int lane = t & 63, wid = t >> 6;

  // ---- one-time init ----
  if (t < 12) smf[S_L + t] = 0.f;
  { int m = t >> 2, hp = 12 + (t & 3); smf[W_L2 + m*16 + hp] = 0.f; }

  // Wb B-fragments (WL folded), bf16, loaded once
  short8 wbf[4];
  {
    int h = lane & 15, kg = lane >> 4;
    #pragma unroll
    for (int ks = 0; ks < 4; ++ks)
      #pragma unroll
      for (int e = 0; e < 8; ++e) {
        int kk = ks*32 + kg*8 + e;
        float v = (h < 12) ? WL * Wb[kk*12 + h] : 0.f;
        wbf[ks][e] = (short)f2bf1(v);
      }
  }

  // C-phase decode: 16 zc-slots x 4 h-quads x 4 m-groups
  int cs = t & 15, chq = (t >> 4) & 3, cmg = t >> 6;
  float cacc[4][8] = {};

  // D-phase decode: 120 float4-columns of [v|vpts] x 2 m-halves
  bool dact = t < 240;
  int mh = t / 120, slot = t % 120;
  const float* dsrc; int dstride, dh;
  if (slot < 48) { dh = slot >> 2;     dsrc = raw + 384 + slot*4;       dstride = 1152; }
  else           { dh = (slot-48) / 6; dsrc = vpts + (slot-48)*4;       dstride = 288;  }
  float da0 = 0.f, da1 = 0.f, da2 = 0.f, da3 = 0.f;

  const float* zrow = z + (size_t)n*768*128;
  int ssm = t >> 5, ssc = t & 31;  // staging: m = i*8 + ssm, cols ssc*4..+3

  float4 zst[8];
  #define STAGE_LOAD(M0)                                                     \
    _Pragma("unroll")                                                        \
    for (int i = 0; i < 8; ++i)                                              \
      zst[i] = *(const float4*)(zrow + (size_t)((M0) + i*8 + ssm)*128 + ssc*4);
  #define STAGE_WRITE()                                                      \
    _Pragma("unroll")                                                        \
    for (int i = 0; i < 8; ++i) {                                            \
      unsigned w0 = f2bf2(zst[i].x, zst[i].y);                               \
      unsigned w1 = f2bf2(zst[i].z, zst[i].w);                               \
      uint2 uu; uu.x = w0; uu.y = w1;                                        \
      *(uint2*)&smem[Z_L + (i*8 + ssm)*68 + ssc*2] = uu;                     \
    }

  STAGE_LOAD(0);
  STAGE_WRITE();
  BAR_LDS();

  const size_t slbase = (size_t)n * 9216;

  for (int it = 0; it < 12; ++it) {
    int m0 = it * 64;
    if (it < 11) { STAGE_LOAD(m0 + 64); }   // stays in flight across LDS-only barriers

    // ---- B1: bias[m][h] = bf16 MFMA z_tile @ Wb ----
    {
      f32x4 bacc = (f32x4){0.f,0.f,0.f,0.f};
      int zbase = (wid*16 + (lane & 15))*68;
      #pragma unroll
      for (int ks = 0; ks < 4; ++ks) {
        short8 za = *(const short8*)&smem[Z_L + zbase + (lane >> 4)*4 + ks*16];
        bacc = __builtin_amdgcn_mfma_f32_16x16x32_bf16(za, wbf[ks], bacc, 0, 0, 0);
      }
      #pragma unroll
      for (int r = 0; r < 4; ++r)
        smf[BIASL + (wid*16 + (lane >> 4)*4 + r)*17 + (lane & 15)] = bacc[r];
    }
    BAR_LDS();

    // ---- B2: p = exp(slog + bias); write [m][h] and transposed [h][m] ----
    #pragma unroll
    for (int i = 0; i < 3; ++i) {
      int idx = i*256 + t, m = idx / 12, h = idx - m*12;
      float sv = slog[slbase + (size_t)(m0 + m)*12 + h];
      float p = __expf(sv + smf[BIASL + m*17 + h]);
      smf[W_L2 + m*16 + h] = p;
      smf[W_MT + h*68 + m] = p;
    }
    BAR_LDS();

    // ---- SM: softmax denominator ----
    if (t < 48) {
      int h = t >> 2, seg = t & 3;
      float ps = 0.f;
      #pragma unroll
      for (int q = 0; q < 4; ++q) {
        float4 v = *(const float4*)&smf[W_MT + h*68 + seg*16 + q*4];
        ps += v.x + v.y + v.z + v.w;
      }
      ps += __shfl_xor(ps, 1);
      ps += __shfl_xor(ps, 2);
      if (seg == 0) smf[S_L + h] += ps;
    }

    // ---- C: o_pair partial accumulate (z bf16x8, p b128) ----
    #pragma unroll 4
    for (int j = 0; j < 16; ++j) {
      int m = cmg*16 + j;
      uint4 zw = *(const uint4*)&smem[Z_L + m*68 + cs*4];
      float4 wv = *(const float4*)&smf[W_L2 + m*16 + chq*4];
      float zf[8];
      zf[0] = bflo(zw.x); zf[1] = bfhi(zw.x);
      zf[2] = bflo(zw.y); zf[3] = bfhi(zw.y);
      zf[4] = bflo(zw.z); zf[5] = bfhi(zw.z);
      zf[6] = bflo(zw.w); zf[7] = bfhi(zw.w);
      float wvv[4] = {wv.x, wv.y, wv.z, wv.w};
      #pragma unroll
      for (int hj = 0; hj < 4; ++hj)
        #pragma unroll
        for (int e = 0; e < 8; ++e)
          cacc[hj][e] += wvv[hj] * zf[e];
    }

    // ---- D: o / o_pts accumulate (float4 column per thread) ----
    if (dact) {
      #pragma unroll
      for (int j4 = 0; j4 < 8; ++j4) {
        float4 wq = *(const float4*)&smf[W_MT + dh*68 + mh*32 + j4*4];
        float wqq[4] = {wq.x, wq.y, wq.z, wq.w};
        #pragma unroll
        for (int e = 0; e < 4; ++e) {
          int row = m0 + mh*32 + j4*4 + e;
          float4 v = *(const float4*)(dsrc + (size_t)row*dstride);
          da0 += wqq[e]*v.x; da1 += wqq[e]*v.y; da2 += wqq[e]*v.z; da3 += wqq[e]*v.w;
        }
      }
    }

    if (it < 11) {
      BAR_LDS();
      STAGE_WRITE();
    }
    BAR_LDS();
  }

  // ---- finalize ----
  float* catn = cat + (size_t)n*2016;
  // phase A: D mh1 partials; C mg2/3 partials (zone = z_l region)
  if (dact && mh == 1) {
    float4 dv; dv.x = da0; dv.y = da1; dv.z = da2; dv.w = da3;
    *(float4*)&smf[DRED + slot*4] = dv;
  }
  if (cmg >= 2) {
    int base = (cmg-2)*2048 + (t & 63)*32;
    #pragma unroll
    for (int j = 0; j < 4; ++j)
      #pragma unroll
      for (int e4 = 0; e4 < 2; ++e4) {
        float4 v; v.x = cacc[j][e4*4+0]; v.y = cacc[j][e4*4+1];
        v.z = cacc[j][e4*4+2]; v.w = cacc[j][e4*4+3];
        *(float4*)&smf[Z_L + base + j*8 + e4*4] = v;
      }
  }
  BAR_LDS();
  // phase B: D mh0 reduce + store o / ogl; C mg0/1 add partials
  if (dact && mh == 0) {
    float4 dr = *(const float4*)&smf[DRED + slot*4];
    float inv = 1.f / smf[S_L + dh];
    float4 o; o.x = (da0+dr.x)*inv; o.y = (da1+dr.y)*inv;
    o.z = (da2+dr.z)*inv; o.w = (da3+dr.w)*inv;
    if (slot < 48) *(float4*)(catn + slot*4) = o;
    else           *(float4*)&smf[OGL + (slot-48)*4] = o;
  }
  if (cmg < 2) {
    int base = cmg*2048 + (t & 63)*32;
    #pragma unroll
    for (int j = 0; j < 4; ++j)
      #pragma unroll
      for (int e = 0; e < 8; ++e)
        cacc[j][e] += smf[Z_L + base + j*8 + e];
  }
  BAR_LDS();
  // phase C: o_pts inverse-frame transform; C mg1 writes zone
  if (cmg == 1) {
    int base = (t & 63)*32;
    #pragma unroll
    for (int j = 0; j < 4; ++j)
      #pragma unroll
      for (int e4 = 0; e4 < 2; ++e4) {
        float4 v; v.x = cacc[j][e4*4+0]; v.y = cacc[j][e4*4+1];
        v.z = cacc[j][e4*4+2]; v.w = cacc[j][e4*4+3];
        *(float4*)&smf[Z_L + base + j*8 + e4*4] = v;
      }
  }
  {
    const float* R9 = Rg + n*9;
    const float* tv = tg + n*3;
    for (int j = t; j < 288; j += 256) {
      int x = j % 3, base = j - x;
      float g0 = smf[OGL + base + 0] - tv[0];
      float g1 = smf[OGL + base + 1] - tv[1];
      float g2 = smf[OGL + base + 2] - tv[2];
      catn[192 + j] = R9[x]*g0 + R9[3+x]*g1 + R9[6+x]*g2;   // R^T (g - t)
    }
  }
  BAR_LDS();
  // phase D: C mg0 final reduce + store o_pair
  if (cmg == 0) {
    int base = (t & 63)*32;
    #pragma unroll
    for (int j = 0; j < 4; ++j)
      #pragma unroll
      for (int e = 0; e < 8; ++e)
        cacc[j][e] += smf[Z_L + base + j*8 + e];
    if (chq < 3) {
      #pragma unroll
      for (int j = 0; j < 4; ++j) {
        int h = chq*4 + j;
        float inv = 1.f / smf[S_L + h];
        #pragma unroll
        for (int e4 = 0; e4 < 2; ++e4) {
          float4 v;
          v.x = cacc[j][e4*4+0]*inv; v.y = cacc[j][e4*4+1]*inv;
          v.z = cacc[j][e4*4+2]*inv; v.w = cacc[j][e4*4+3]*inv;
          *(float4*)(catn + 480 + h*128 + cs*8 + e4*4) = v;
        }
      }
    }
  }
}

// ---------------- kernel 6: cat @ W_out (split-K x4) ----------------
__global__ __launch_bounds__(256) void final_gemm(
    const float* __restrict__ cat, const float* __restrict__ Wout, float* __restrict__ partial)
{
  int t = threadIdx.x, b = blockIdx.x;
  int ct = b % 6, rt = (b / 6) % 12, ks = b / 72;
  int r0 = rt*64, c0 = ct*64, kbase = ks*504;
  __shared__ float a_l[64*25];
  __shared__ float b_l[24*65];
  float acc[4][4] = {};
  int tr = t >> 4, tc = t & 15;
  for (int kt = 0; kt < 504; kt += 24) {
    int k0 = kbase + kt;
    #pragma unroll
    for (int i = 0; i < 6; ++i) {
      int idx = i*256 + t;
      int r = idx / 24, kk = idx % 24;
      a_l[r*25 + kk] = cat[(size_t)(r0 + r)*2016 + k0 + kk];
      int kk2 = idx >> 6, c = idx & 63;
      b_l[kk2*65 + c] = Wout[(size_t)(k0 + kk2)*384 + c0 + c];
    }
    __syncthreads();
    #pragma unroll
    for (int kk = 0; kk < 24; ++kk) {
      float a[4], bb[4];
      #pragma unroll
      for (int i = 0; i < 4; ++i) a[i] = a_l[(tr*4+i)*25 + kk];
      #pragma unroll
      for (int j = 0; j < 4; ++j) bb[j] = b_l[kk*65 + tc*4 + j];
      #pragma unroll
      for (int i = 0; i < 4; ++i)
        #pragma unroll
        for (int j = 0; j < 4; ++j) acc[i][j] += a[i]*bb[j];
    }
    __syncthreads();
  }
  float* po = partial + (size_t)ks*294912;
  #pragma unroll
  for (int i = 0; i < 4; ++i)
    #pragma unroll
    for (int j = 0; j < 4; ++j)
      po[(r0 + tr*4 + i)*384 + c0 + tc*4 + j] = acc[i][j];
}

// ---------------- kernel 7: reduce partials + bias ----------------
__global__ __launch_bounds__(256) void reduce_out(
    const float* __restrict__ partial, const float* __restrict__ b_out, float* __restrict__ out)
{
  int i = blockIdx.x*256 + threadIdx.x;
  out[i] = b_out[i % 384] + partial[i] + partial[294912 + i]
         + partial[2*294912 + i] + partial[3*294912 + i];
}

extern "C" void kernel_launch(void* const* d_in, const int* in_sizes, int n_in,
                              void* d_out, int out_size, void* d_ws, size_t ws_size,
                              hipStream_t stream) {
  const float* s    = (const float*)d_in[0];
  const float* z    = (const float*)d_in[1];
  const float* R    = (const float*)d_in[2];
  const float* tv   = (const float*)d_in[3];
  const float* Wq   = (const float*)d_in[4];
  const float* Wk   = (const float*)d_in[5];
  const float* Wv   = (const float*)d_in[6];
  const float* Wqp  = (const float*)d_in[7];
  const float* Wkp  = (const float*)d_in[8];
  const float* Wvp  = (const float*)d_in[9];
  const float* Wb   = (const float*)d_in[10];
  const float* Wout = (const float*)d_in[11];
  const float* bout = (const float*)d_in[12];
  float* out = (float*)d_out;
  float* ws  = (float*)d_ws;

  float* raw  = ws + RAW_OFF;
  float* qpts = ws + QPTS_OFF;
  float* kpts = ws + KPTS_OFF;
  float* vpts = ws + VPTS_OFF;
  float* qn   = ws + QN_OFF;
  float* kn   = ws + KN_OFF;
  float* cat  = ws + CAT_OFF;
  short* Qp   = (short*)(ws + QP_OFF);
  short* Kp   = (short*)(ws + KP_OFF);
  float* slog = ws + SLOG_OFF;
  float* partial = ws + PART_OFF;

  prep_gemm<<<576, 256, 0, stream>>>(s, Wq, Wk, Wv, Wqp, Wkp, Wvp, raw);
  transform_pts<<<768, 256, 0, stream>>>(raw, R, tv, qpts, kpts, vpts, qn, kn);
  qkprep<<<768, 384, 0, stream>>>(raw, qpts, kpts, Qp, Kp);
  logits_gemm<<<144, 512, 0, stream>>>(Qp, Kp, kn, slog);
  ipa_main<<<768, 256, 0, stream>>>(z, raw, slog, vpts, Wb, R, tv, cat);
  final_gemm<<<288, 256, 0, stream>>>(cat, Wout, partial);
  reduce_out<<<1152, 256, 0, stream>>>(partial, bout, out);
}

// Round 6
// 264.515 us; speedup vs baseline: 2.5384x; 1.5990x over previous
//
#include <hip/hip_runtime.h>
#include <math.h>

// IPA: B=1, N=768, H=12, C=16, PQ=4, PV=8, C_S=384, C_Z=128
// ws layout (floats):
#define RAW_OFF   0u          // [768][1152] q|k|v|qp|kp|vp
#define QPTS_OFF  884736u     // [768][144]
#define KPTS_OFF  995328u     // [768][144]
#define VPTS_OFF  1105920u    // [768][288]
#define QN_OFF    1327104u    // [768][12] (unused downstream, kept)
#define KN_OFF    1336320u    // [768][12]
#define CAT_OFF   1345536u    // [768][2016]
#define QP_OFF    2893824u    // bf16 [768][12][32] (147456 float slots)
#define KP_OFF    3041280u    // bf16 [768][12][32]
#define SLOG_OFF  3188736u    // f32 [768][768][12] = 7077888 floats
#define PART_OFF  3188736u    // alias slog (dead by final_gemm)
// total ws: 10,266,624 floats = 41.1 MB

#define WL 0.5773502691896258f    // sqrt(1/3)
#define WC 0.23570226039551587f   // sqrt(2/(9*4))
#define CKN (-0.5f*WL*WC)

typedef __attribute__((ext_vector_type(8))) short short8;
typedef __attribute__((ext_vector_type(4))) float f32x4;

__device__ __forceinline__ unsigned short f2bf1(float a) {
  unsigned u = __builtin_bit_cast(unsigned, a);
  return (unsigned short)((u + 0x7fff + ((u >> 16) & 1)) >> 16);
}
__device__ __forceinline__ unsigned f2bf2(float a, float b) {
  unsigned ua = __builtin_bit_cast(unsigned, a), ub = __builtin_bit_cast(unsigned, b);
  return (unsigned)((ua + 0x7fff + ((ua >> 16) & 1)) >> 16)
       | ((ub + 0x7fff + ((ub >> 16) & 1)) & 0xffff0000u);
}
__device__ __forceinline__ float bflo(unsigned u) { return __builtin_bit_cast(float, u << 16); }
__device__ __forceinline__ float bfhi(unsigned u) { return __builtin_bit_cast(float, u & 0xffff0000u); }

// LDS-only barrier: waitcnt+barrier in ONE asm so nothing schedules between
// them and no memory op crosses either side. Leaves global loads in flight.
#define BAR_LDS() asm volatile("s_waitcnt lgkmcnt(0)\n\ts_barrier" ::: "memory")

// ---------------- kernel 1: s @ [Wq|Wk|Wv|Wqp|Wkp|Wvp] -> raw ----------------
__global__ __launch_bounds__(256) void prep_gemm(
    const float* __restrict__ s, const float* __restrict__ Wq, const float* __restrict__ Wk,
    const float* __restrict__ Wv, const float* __restrict__ Wqp, const float* __restrict__ Wkp,
    const float* __restrict__ Wvp, float* __restrict__ raw)
{
  int t = threadIdx.x;
  int bc = blockIdx.x % 24, br = blockIdx.x / 24;
  int row0 = br * 32, cb = bc * 48;
  const float* W; int outdim, c0;
  if (cb < 192)      { W = Wq;  outdim = 192; c0 = cb; }
  else if (cb < 384) { W = Wk;  outdim = 192; c0 = cb - 192; }
  else if (cb < 576) { W = Wv;  outdim = 192; c0 = cb - 384; }
  else if (cb < 720) { W = Wqp; outdim = 144; c0 = cb - 576; }
  else if (cb < 864) { W = Wkp; outdim = 144; c0 = cb - 720; }
  else               { W = Wvp; outdim = 288; c0 = cb - 864; }

  __shared__ float s_l[32*33];
  __shared__ float w_l[32*49];
  float acc[2][3] = {};
  int tr = t >> 4, tc = t & 15;

  for (int k0 = 0; k0 < 384; k0 += 32) {
    #pragma unroll
    for (int i = 0; i < 4; ++i) {
      int idx = i*256 + t, r = idx >> 5, kk = idx & 31;
      s_l[r*33 + kk] = s[(row0 + r)*384 + k0 + kk];
    }
    #pragma unroll
    for (int i = 0; i < 6; ++i) {
      int idx = i*256 + t, kk = idx / 48, c = idx % 48;
      w_l[kk*49 + c] = W[(k0 + kk)*outdim + c0 + c];
    }
    __syncthreads();
    #pragma unroll
    for (int kk = 0; kk < 32; ++kk) {
      float a0 = s_l[(tr*2+0)*33 + kk], a1 = s_l[(tr*2+1)*33 + kk];
      float b0 = w_l[kk*49 + tc*3 + 0], b1 = w_l[kk*49 + tc*3 + 1], b2 = w_l[kk*49 + tc*3 + 2];
      acc[0][0] += a0*b0; acc[0][1] += a0*b1; acc[0][2] += a0*b2;
      acc[1][0] += a1*b0; acc[1][1] += a1*b1; acc[1][2] += a1*b2;
    }
    __syncthreads();
  }
  #pragma unroll
  for (int i = 0; i < 2; ++i)
    #pragma unroll
    for (int j = 0; j < 3; ++j)
      raw[(row0 + tr*2 + i)*1152 + cb + tc*3 + j] = acc[i][j];
}

// ---------------- kernel 2: frame transform + point norms ----------------
__global__ __launch_bounds__(256) void transform_pts(
    const float* __restrict__ raw, const float* __restrict__ R, const float* __restrict__ tg,
    float* __restrict__ qpts, float* __restrict__ kpts, float* __restrict__ vpts,
    float* __restrict__ qn, float* __restrict__ kn)
{
  int n = blockIdx.x, t = threadIdx.x;
  __shared__ float tl[576];
  const float* R9 = R + n*9;
  const float* tv = tg + n*3;
  for (int i = 0; i < 3; ++i) {
    int j = i*256 + t;
    if (j >= 576) break;
    int jj, basecol; float* dst; int dstoff;
    if (j < 144)      { jj = j;      basecol = 576; dst = qpts; dstoff = n*144 + jj; }
    else if (j < 288) { jj = j-144;  basecol = 720; dst = kpts; dstoff = n*144 + jj; }
    else              { jj = j-288;  basecol = 864; dst = vpts; dstoff = n*288 + jj; }
    int x = jj % 3;
    const float* p = raw + n*1152 + basecol + (jj - x);
    float val = R9[x*3+0]*p[0] + R9[x*3+1]*p[1] + R9[x*3+2]*p[2] + tv[x];
    dst[dstoff] = val;
    tl[j] = val;
  }
  __syncthreads();
  if (t < 24) {
    int side = t / 12, h = t % 12;
    const float* q = tl + side*144 + h*12;
    float sm = 0.f;
    #pragma unroll
    for (int r = 0; r < 12; ++r) sm += q[r]*q[r];
    (side == 0 ? qn : kn)[n*12 + h] = sm;
  }
}

// ---------------- kernel 3: build Qp/Kp bf16 [n][h][32] ----------------
// Qp = [WL*0.25*q(16) | WL*WC*qpts(12) | 0,0,0,0], Kp = [k | kpts | 0...]
__global__ __launch_bounds__(384) void qkprep(
    const float* __restrict__ raw, const float* __restrict__ qpts,
    const float* __restrict__ kpts, short* __restrict__ Qp, short* __restrict__ Kp)
{
  int n = blockIdx.x, t = threadIdx.x;
  int h = t >> 5, k = t & 31;
  float qv, kv;
  // raw cols: q 0..191, k 192..383, v 384..575
  if (k < 16)      { qv = (WL*0.25f) * raw[n*1152 + h*16 + k];       kv = raw[n*1152 + 192 + h*16 + k]; }
  else if (k < 28) { qv = (WL*WC) * qpts[n*144 + h*12 + (k-16)];     kv = kpts[n*144 + h*12 + (k-16)]; }
  else             { qv = 0.f; kv = 0.f; }
  Qp[n*384 + t] = (short)f2bf1(qv);
  Kp[n*384 + t] = (short)f2bf1(kv);
}

// ---------------- kernel 4: slog[n][m][12] = WL*(qk/4 + WC*cross) + CKN*kn ----------------
// per-h bf16 MFMA GEMM 768x768x32; block = 64x64 tile, 8 waves (4 nsub x 2 msub)
__global__ __launch_bounds__(512) void logits_gemm(
    const short* __restrict__ Qp, const short* __restrict__ Kp,
    const float* __restrict__ kn, float* __restrict__ slog)
{
  int t = threadIdx.x, b = blockIdx.x;
  int bn = b / 12, bm = b % 12;
  int lane = t & 63, wid = t >> 6;
  int nsub = wid & 3, msub = wid >> 2;
  int l15 = lane & 15, kg = lane >> 4;
  int nrow = bn*64 + nsub*16 + l15;
  int mbase = bm*64 + msub*32;

  f32x4 acc[2][12];
  #pragma unroll
  for (int mt = 0; mt < 2; ++mt)
    #pragma unroll
    for (int h = 0; h < 12; ++h) acc[mt][h] = (f32x4){0.f,0.f,0.f,0.f};

  #pragma unroll
  for (int h = 0; h < 12; ++h) {
    short8 af = *(const short8*)(Qp + (size_t)(nrow*12 + h)*32 + kg*8);
    #pragma unroll
    for (int mt = 0; mt < 2; ++mt) {
      int m = mbase + mt*16 + l15;
      short8 bf = *(const short8*)(Kp + (size_t)(m*12 + h)*32 + kg*8);
      acc[mt][h] = __builtin_amdgcn_mfma_f32_16x16x32_bf16(af, bf, acc[mt][h], 0, 0, 0);
    }
  }
  #pragma unroll
  for (int mt = 0; mt < 2; ++mt) {
    int m = mbase + mt*16 + l15;
    float knadj[12];
    #pragma unroll
    for (int h = 0; h < 12; ++h) knadj[h] = CKN * kn[m*12 + h];
    #pragma unroll
    for (int r = 0; r < 4; ++r) {
      int nr = bn*64 + nsub*16 + kg*4 + r;
      size_t base = ((size_t)nr*768 + m)*12;
      #pragma unroll
      for (int hq = 0; hq < 3; ++hq) {
        float4 v;
        v.x = acc[mt][hq*4+0][r] + knadj[hq*4+0];
        v.y = acc[mt][hq*4+1][r] + knadj[hq*4+1];
        v.z = acc[mt][hq*4+2][r] + knadj[hq*4+2];
        v.w = acc[mt][hq*4+3][r] + knadj[hq*4+3];
        *(float4*)(slog + base + hq*4) = v;
      }
    }
  }
}

// ---------------- kernel 5: fused attention core ----------------
// LDS (u32 words): z_l bf16 [64][pitch68w], bias[64][17], w_l2[64][16],
//                  w_mt[16][68], S[12], ogl[288], dred[480]
#define Z_L   0
#define BIASL 4352
#define W_L2  5440
#define W_MT  6464
#define S_L   7552
#define OGL   7564
#define DRED  7852
#define SMEMW 8332

// launch_bounds(256, 2): ROUND-6 FIX -- (256,4) made the heuristic target a
// 64-VGPR budget and spill the 32-reg zst prefetch to scratch every iter
// (~680 MB of HBM scratch traffic, WRITE_SIZE 462 MB). Budget 256 regs; actual
// occupancy stays LDS-capped (~4 blocks/CU).
__global__ __launch_bounds__(256, 2) void ipa_main(
    const float* __restrict__ z, const float* __restrict__ raw,
    const float* __restrict__ slog, const float* __restrict__ vpts,
    const float* __restrict__ Wb, const float* __restrict__ Rg,
    const float* __restrict__ tg, float* __restrict__ cat)
{
  __shared__ __align__(16) unsigned smem[SMEMW];
  float* smf = (float*)smem;
  int n = blockIdx.x, t = threadIdx.x;
  int lane = t & 63, wid = t >> 6;

  // ---- one-time init ----
  if (t < 12) smf[S_L + t] = 0.f;
  { int m = t >> 2, hp = 12 + (t & 3); smf[W_L2 + m*16 + hp] = 0.f; }

  // Wb B-fragments (WL folded), bf16, loaded once
  short8 wbf[4];
  {
    int h = lane & 15, kg = lane >> 4;
    #pragma unroll
    for (int ks = 0; ks < 4; ++ks)
      #pragma unroll
      for (int e = 0; e < 8; ++e) {
        int kk = ks*32 + kg*8 + e;
        float v = (h < 12) ? WL * Wb[kk*12 + h] : 0.f;
        wbf[ks][e] = (short)f2bf1(v);
      }
  }

  // C-phase decode: 16 zc-slots x 4 h-quads x 4 m-groups
  int cs = t & 15, chq = (t >> 4) & 3, cmg = t >> 6;
  float cacc[4][8] = {};

  // D-phase decode: 120 float4-columns of [v|vpts] x 2 m-halves
  bool dact = t < 240;
  int mh = t / 120, slot = t % 120;
  const float* dsrc; int dstride, dh;
  if (slot < 48) { dh = slot >> 2;     dsrc = raw + 384 + slot*4;       dstride = 1152; }
  else           { dh = (slot-48) / 6; dsrc = vpts + (slot-48)*4;       dstride = 288;  }
  float da0 = 0.f, da1 = 0.f, da2 = 0.f, da3 = 0.f;

  const float* zrow = z + (size_t)n*768*128;
  int ssm = t >> 5, ssc = t & 31;  // staging: m = i*8 + ssm, cols ssc*4..+3

  float4 zst[8];
  #define STAGE_LOAD(M0)                                                     \
    _Pragma("unroll")                                                        \
    for (int i = 0; i < 8; ++i)                                              \
      zst[i] = *(const float4*)(zrow + (size_t)((M0) + i*8 + ssm)*128 + ssc*4);
  #define STAGE_WRITE()                                                      \
    _Pragma("unroll")                                                        \
    for (int i = 0; i < 8; ++i) {                                            \
      unsigned w0 = f2bf2(zst[i].x, zst[i].y);                               \
      unsigned w1 = f2bf2(zst[i].z, zst[i].w);                               \
      uint2 uu; uu.x = w0; uu.y = w1;                                        \
      *(uint2*)&smem[Z_L + (i*8 + ssm)*68 + ssc*2] = uu;                     \
    }

  STAGE_LOAD(0);
  STAGE_WRITE();
  BAR_LDS();

  const size_t slbase = (size_t)n * 9216;

  for (int it = 0; it < 12; ++it) {
    int m0 = it * 64;
    if (it < 11) { STAGE_LOAD(m0 + 64); }   // stays in flight across LDS-only barriers

    // ---- B1: bias[m][h] = bf16 MFMA z_tile @ Wb ----
    {
      f32x4 bacc = (f32x4){0.f,0.f,0.f,0.f};
      int zbase = (wid*16 + (lane & 15))*68;
      #pragma unroll
      for (int ks = 0; ks < 4; ++ks) {
        short8 za = *(const short8*)&smem[Z_L + zbase + (lane >> 4)*4 + ks*16];
        bacc = __builtin_amdgcn_mfma_f32_16x16x32_bf16(za, wbf[ks], bacc, 0, 0, 0);
      }
      #pragma unroll
      for (int r = 0; r < 4; ++r)
        smf[BIASL + (wid*16 + (lane >> 4)*4 + r)*17 + (lane & 15)] = bacc[r];
    }
    BAR_LDS();

    // ---- B2: p = exp(slog + bias); write [m][h] and transposed [h][m] ----
    #pragma unroll
    for (int i = 0; i < 3; ++i) {
      int idx = i*256 + t, m = idx / 12, h = idx - m*12;
      float sv = slog[slbase + (size_t)(m0 + m)*12 + h];
      float p = __expf(sv + smf[BIASL + m*17 + h]);
      smf[W_L2 + m*16 + h] = p;
      smf[W_MT + h*68 + m] = p;
    }
    BAR_LDS();

    // ---- SM: softmax denominator ----
    if (t < 48) {
      int h = t >> 2, seg = t & 3;
      float ps = 0.f;
      #pragma unroll
      for (int q = 0; q < 4; ++q) {
        float4 v = *(const float4*)&smf[W_MT + h*68 + seg*16 + q*4];
        ps += v.x + v.y + v.z + v.w;
      }
      ps += __shfl_xor(ps, 1);
      ps += __shfl_xor(ps, 2);
      if (seg == 0) smf[S_L + h] += ps;
    }

    // ---- C: o_pair partial accumulate (z bf16x8, p b128) ----
    #pragma unroll 4
    for (int j = 0; j < 16; ++j) {
      int m = cmg*16 + j;
      uint4 zw = *(const uint4*)&smem[Z_L + m*68 + cs*4];
      float4 wv = *(const float4*)&smf[W_L2 + m*16 + chq*4];
      float zf[8];
      zf[0] = bflo(zw.x); zf[1] = bfhi(zw.x);
      zf[2] = bflo(zw.y); zf[3] = bfhi(zw.y);
      zf[4] = bflo(zw.z); zf[5] = bfhi(zw.z);
      zf[6] = bflo(zw.w); zf[7] = bfhi(zw.w);
      float wvv[4] = {wv.x, wv.y, wv.z, wv.w};
      #pragma unroll
      for (int hj = 0; hj < 4; ++hj)
        #pragma unroll
        for (int e = 0; e < 8; ++e)
          cacc[hj][e] += wvv[hj] * zf[e];
    }

    // ---- D: o / o_pts accumulate (float4 column per thread) ----
    if (dact) {
      #pragma unroll
      for (int j4 = 0; j4 < 8; ++j4) {
        float4 wq = *(const float4*)&smf[W_MT + dh*68 + mh*32 + j4*4];
        float wqq[4] = {wq.x, wq.y, wq.z, wq.w};
        #pragma unroll
        for (int e = 0; e < 4; ++e) {
          int row = m0 + mh*32 + j4*4 + e;
          float4 v = *(const float4*)(dsrc + (size_t)row*dstride);
          da0 += wqq[e]*v.x; da1 += wqq[e]*v.y; da2 += wqq[e]*v.z; da3 += wqq[e]*v.w;
        }
      }
    }

    if (it < 11) {
      BAR_LDS();
      STAGE_WRITE();
    }
    BAR_LDS();
  }

  // ---- finalize ----
  float* catn = cat + (size_t)n*2016;
  // phase A: D mh1 partials; C mg2/3 partials (zone = z_l region)
  if (dact && mh == 1) {
    float4 dv; dv.x = da0; dv.y = da1; dv.z = da2; dv.w = da3;
    *(float4*)&smf[DRED + slot*4] = dv;
  }
  if (cmg >= 2) {
    int base = (cmg-2)*2048 + (t & 63)*32;
    #pragma unroll
    for (int j = 0; j < 4; ++j)
      #pragma unroll
      for (int e4 = 0; e4 < 2; ++e4) {
        float4 v; v.x = cacc[j][e4*4+0]; v.y = cacc[j][e4*4+1];
        v.z = cacc[j][e4*4+2]; v.w = cacc[j][e4*4+3];
        *(float4*)&smf[Z_L + base + j*8 + e4*4] = v;
      }
  }
  BAR_LDS();
  // phase B: D mh0 reduce + store o / ogl; C mg0/1 add partials
  if (dact && mh == 0) {
    float4 dr = *(const float4*)&smf[DRED + slot*4];
    float inv = 1.f / smf[S_L + dh];
    float4 o; o.x = (da0+dr.x)*inv; o.y = (da1+dr.y)*inv;
    o.z = (da2+dr.z)*inv; o.w = (da3+dr.w)*inv;
    if (slot < 48) *(float4*)(catn + slot*4) = o;
    else           *(float4*)&smf[OGL + (slot-48)*4] = o;
  }
  if (cmg < 2) {
    int base = cmg*2048 + (t & 63)*32;
    #pragma unroll
    for (int j = 0; j < 4; ++j)
      #pragma unroll
      for (int e = 0; e < 8; ++e)
        cacc[j][e] += smf[Z_L + base + j*8 + e];
  }
  BAR_LDS();
  // phase C: o_pts inverse-frame transform; C mg1 writes zone
  if (cmg == 1) {
    int base = (t & 63)*32;
    #pragma unroll
    for (int j = 0; j < 4; ++j)
      #pragma unroll
      for (int e4 = 0; e4 < 2; ++e4) {
        float4 v; v.x = cacc[j][e4*4+0]; v.y = cacc[j][e4*4+1];
        v.z = cacc[j][e4*4+2]; v.w = cacc[j][e4*4+3];
        *(float4*)&smf[Z_L + base + j*8 + e4*4] = v;
      }
  }
  {
    const float* R9 = Rg + n*9;
    const float* tv = tg + n*3;
    for (int j = t; j < 288; j += 256) {
      int x = j % 3, base = j - x;
      float g0 = smf[OGL + base + 0] - tv[0];
      float g1 = smf[OGL + base + 1] - tv[1];
      float g2 = smf[OGL + base + 2] - tv[2];
      catn[192 + j] = R9[x]*g0 + R9[3+x]*g1 + R9[6+x]*g2;   // R^T (g - t)
    }
  }
  BAR_LDS();
  // phase D: C mg0 final reduce + store o_pair
  if (cmg == 0) {
    int base = (t & 63)*32;
    #pragma unroll
    for (int j = 0; j < 4; ++j)
      #pragma unroll
      for (int e = 0; e < 8; ++e)
        cacc[j][e] += smf[Z_L + base + j*8 + e];
    if (chq < 3) {
      #pragma unroll
      for (int j = 0; j < 4; ++j) {
        int h = chq*4 + j;
        float inv = 1.f / smf[S_L + h];
        #pragma unroll
        for (int e4 = 0; e4 < 2; ++e4) {
          float4 v;
          v.x = cacc[j][e4*4+0]*inv; v.y = cacc[j][e4*4+1]*inv;
          v.z = cacc[j][e4*4+2]*inv; v.w = cacc[j][e4*4+3]*inv;
          *(float4*)(catn + 480 + h*128 + cs*8 + e4*4) = v;
        }
      }
    }
  }
}

// ---------------- kernel 6: cat @ W_out (split-K x4) ----------------
__global__ __launch_bounds__(256) void final_gemm(
    const float* __restrict__ cat, const float* __restrict__ Wout, float* __restrict__ partial)
{
  int t = threadIdx.x, b = blockIdx.x;
  int ct = b % 6, rt = (b / 6) % 12, ks = b / 72;
  int r0 = rt*64, c0 = ct*64, kbase = ks*504;
  __shared__ float a_l[64*25];
  __shared__ float b_l[24*65];
  float acc[4][4] = {};
  int tr = t >> 4, tc = t & 15;
  for (int kt = 0; kt < 504; kt += 24) {
    int k0 = kbase + kt;
    #pragma unroll
    for (int i = 0; i < 6; ++i) {
      int idx = i*256 + t;
      int r = idx / 24, kk = idx % 24;
      a_l[r*25 + kk] = cat[(size_t)(r0 + r)*2016 + k0 + kk];
      int kk2 = idx >> 6, c = idx & 63;
      b_l[kk2*65 + c] = Wout[(size_t)(k0 + kk2)*384 + c0 + c];
    }
    __syncthreads();
    #pragma unroll
    for (int kk = 0; kk < 24; ++kk) {
      float a[4], bb[4];
      #pragma unroll
      for (int i = 0; i < 4; ++i) a[i] = a_l[(tr*4+i)*25 + kk];
      #pragma unroll
      for (int j = 0; j < 4; ++j) bb[j] = b_l[kk*65 + tc*4 + j];
      #pragma unroll
      for (int i = 0; i < 4; ++i)
        #pragma unroll
        for (int j = 0; j < 4; ++j) acc[i][j] += a[i]*bb[j];
    }
    __syncthreads();
  }
  float* po = partial + (size_t)ks*294912;
  #pragma unroll
  for (int i = 0; i < 4; ++i)
    #pragma unroll
    for (int j = 0; j < 4; ++j)
      po[(r0 + tr*4 + i)*384 + c0 + tc*4 + j] = acc[i][j];
}

// ---------------- kernel 7: reduce partials + bias ----------------
__global__ __launch_bounds__(256) void reduce_out(
    const float* __restrict__ partial, const float* __restrict__ b_out, float* __restrict__ out)
{
  int i = blockIdx.x*256 + threadIdx.x;
  out[i] = b_out[i % 384] + partial[i] + partial[294912 + i]
         + partial[2*294912 + i] + partial[3*294912 + i];
}

extern "C" void kernel_launch(void* const* d_in, const int* in_sizes, int n_in,
                              void* d_out, int out_size, void* d_ws, size_t ws_size,
                              hipStream_t stream) {
  const float* s    = (const float*)d_in[0];
  const float* z    = (const float*)d_in[1];
  const float* R    = (const float*)d_in[2];
  const float* tv   = (const float*)d_in[3];
  const float* Wq   = (const float*)d_in[4];
  const float* Wk   = (const float*)d_in[5];
  const float* Wv   = (const float*)d_in[6];
  const float* Wqp  = (const float*)d_in[7];
  const float* Wkp  = (const float*)d_in[8];
  const float* Wvp  = (const float*)d_in[9];
  const float* Wb   = (const float*)d_in[10];
  const float* Wout = (const float*)d_in[11];
  const float* bout = (const float*)d_in[12];
  float* out = (float*)d_out;
  float* ws  = (float*)d_ws;

  float* raw  = ws + RAW_OFF;
  float* qpts = ws + QPTS_OFF;
  float* kpts = ws + KPTS_OFF;
  float* vpts = ws + VPTS_OFF;
  float* qn   = ws + QN_OFF;
  float* kn   = ws + KN_OFF;
  float* cat  = ws + CAT_OFF;
  short* Qp   = (short*)(ws + QP_OFF);
  short* Kp   = (short*)(ws + KP_OFF);
  float* slog = ws + SLOG_OFF;
  float* partial = ws + PART_OFF;

  prep_gemm<<<576, 256, 0, stream>>>(s, Wq, Wk, Wv, Wqp, Wkp, Wvp, raw);
  transform_pts<<<768, 256, 0, stream>>>(raw, R, tv, qpts, kpts, vpts, qn, kn);
  qkprep<<<768, 384, 0, stream>>>(raw, qpts, kpts, Qp, Kp);
  logits_gemm<<<144, 512, 0, stream>>>(Qp, Kp, kn, slog);
  ipa_main<<<768, 256, 0, stream>>>(z, raw, slog, vpts, Wb, R, tv, cat);
  final_gemm<<<288, 256, 0, stream>>>(cat, Wout, partial);
  reduce_out<<<1152, 256, 0, stream>>>(partial, bout, out);
}